// Round 9
// baseline (31.571 us; speedup 1.0000x reference)
//
#include <hip/hip_runtime.h>

// Problem constants: B=16, T=64, N=128, D=512, H=512, O=256, A=18
#define DD 512
#define HH 512
#define OO 256
#define AA 18
#define ROWS 1024

typedef __attribute__((ext_vector_type(8))) short bf16x8;
typedef __attribute__((ext_vector_type(4))) float f32x4;

// f32 -> bf16 round-to-nearest-even (bit trick; inputs are finite).
__device__ __forceinline__ unsigned short f2bf(float x) {
  unsigned u = __builtin_bit_cast(unsigned, x);
  u += 0x7FFFu + ((u >> 16) & 1u);
  return (unsigned short)(u >> 16);
}

// ---------------------------------------------------------------------------
// k1: per block (ct = col-tile 0..15, rt = row-tile 0..15):
//   (1) GEMM1 tile: G[64 rows][32 cols] = obs[64][512] @ W1[512][32 cols]
//       (MFMA 16x16x32_bf16, 2 K-groups x 4 waves, 8-tile pipeline each)
//   (2) path-GCN layer-1 combine -> U-tile (bf16, LDS only; 64 rows == one
//       batch so t == local row, neighbors in-tile)
//   (3) GEMM2 K-slice partial: Pp[ct][64 rows][256] = U-tile @ W2[32 slice][256]
// Grid: 256 blocks x 512 threads.
// ---------------------------------------------------------------------------
__global__ __launch_bounds__(512) void k1_mega(
    const float* __restrict__ obs, const float* __restrict__ W1,
    const float* __restrict__ b1, const float* __restrict__ W2,
    float* __restrict__ Pp) {
  __shared__ unsigned short As[2][64][40];
  __shared__ unsigned short Bt[2][32][40];
  __shared__ float Gs[64][36];
  __shared__ unsigned short Ut[64][40];
  __shared__ unsigned short W2t[256][40];

  const int tid = threadIdx.x;
  const int g = tid >> 8;              // K-group for GEMM1
  const int gt = tid & 255;
  const int lane = tid & 63;
  const int wid = (tid >> 6) & 3;      // wave within K-group
  const int w8 = tid >> 6;             // wave 0..7
  const int ct = blockIdx.x & 15;
  const int col0 = ct * 32;
  const int row0 = (blockIdx.x >> 4) * 64;
  const int k0 = g * 256;

  const int sar = gt >> 2, sak = (gt & 3) * 8;    // A staging: row, k-ofs
  const int sbc = gt & 31, sbk = (gt >> 5) * 4;   // B staging: col, k-ofs
  const int lr = lane & 15, lk = (lane >> 4) * 8; // fragment indices

  for (int i = tid; i < 64 * 36; i += 512) ((float*)Gs)[i] = 0.f;

  float4 pa0, pa1;
  float pb0, pb1, pb2, pb3;
  f32x4 acc0 = {0.f, 0.f, 0.f, 0.f}, acc1 = {0.f, 0.f, 0.f, 0.f};

#define LOADG(kb)                                                              \
  {                                                                            \
    const float* Ap = &obs[(size_t)(row0 + sar) * DD + (kb) + sak];            \
    pa0 = *reinterpret_cast<const float4*>(Ap);                                \
    pa1 = *reinterpret_cast<const float4*>(Ap + 4);                            \
    const float* Bp = &W1[(size_t)((kb) + sbk) * HH + col0 + sbc];             \
    pb0 = Bp[0]; pb1 = Bp[HH]; pb2 = Bp[2 * HH]; pb3 = Bp[3 * HH];             \
  }
#define STOLDS()                                                               \
  {                                                                            \
    bf16x8 v;                                                                  \
    v[0] = (short)f2bf(pa0.x); v[1] = (short)f2bf(pa0.y);                      \
    v[2] = (short)f2bf(pa0.z); v[3] = (short)f2bf(pa0.w);                      \
    v[4] = (short)f2bf(pa1.x); v[5] = (short)f2bf(pa1.y);                      \
    v[6] = (short)f2bf(pa1.z); v[7] = (short)f2bf(pa1.w);                      \
    *reinterpret_cast<bf16x8*>(&As[g][sar][sak]) = v;                          \
    ushort4 w;                                                                 \
    w.x = f2bf(pb0); w.y = f2bf(pb1); w.z = f2bf(pb2); w.w = f2bf(pb3);        \
    *reinterpret_cast<ushort4*>(&Bt[g][sbc][sbk]) = w;                         \
  }
#define COMPUTE()                                                              \
  {                                                                            \
    const bf16x8 af = *reinterpret_cast<const bf16x8*>(&As[g][wid * 16 + lr][lk]); \
    const bf16x8 bf0 = *reinterpret_cast<const bf16x8*>(&Bt[g][lr][lk]);       \
    const bf16x8 bf1 = *reinterpret_cast<const bf16x8*>(&Bt[g][16 + lr][lk]);  \
    acc0 = __builtin_amdgcn_mfma_f32_16x16x32_bf16(af, bf0, acc0, 0, 0, 0);    \
    acc1 = __builtin_amdgcn_mfma_f32_16x16x32_bf16(af, bf1, acc1, 0, 0, 0);    \
  }

  LOADG(k0);
  STOLDS();
  __syncthreads();
  for (int tt = 1; tt < 8; ++tt) {
    LOADG(k0 + tt * 32);
    COMPUTE();
    __syncthreads();
    STOLDS();
    __syncthreads();
  }
  COMPUTE();
  __syncthreads();
#undef LOADG
#undef STOLDS
#undef COMPUTE

  // Issue the W2 K-slice loads now (latency hides under merge+combine).
  // thread: n = tid&255, kq = tid>>8; covers W2[col0 .. col0+31][0..255].
  float w2r[16];
  {
    const int n = tid & 255, kq = tid >> 8;
    const float* Wp = &W2[(size_t)(col0 + kq * 16) * OO + n];
#pragma unroll
    for (int kk = 0; kk < 16; ++kk) w2r[kk] = Wp[(size_t)kk * OO];
  }

  // Merge both K-groups' accumulators into Gs (f32).
  // C/D layout: col = lane&15, row = (lane>>4)*4 + reg.
  {
    const int crow = wid * 16 + (lane >> 4) * 4;
#pragma unroll
    for (int i = 0; i < 4; ++i) atomicAdd(&Gs[crow + i][lr], acc0[i]);
#pragma unroll
    for (int i = 0; i < 4; ++i) atomicAdd(&Gs[crow + i][16 + lr], acc1[i]);
  }
  __syncthreads();

  // Path-GCN layer-1 combine -> Ut (bf16, LDS). t == local row.
  {
    const int rr = tid >> 3;
    const int c4 = (tid & 7) * 4;
    const int t = rr;
    const float is6 = 0.4082482904638630f;  // 1/sqrt(6)
    float c0, c1, c2, d1, d2, al, be;
    if (t <= 1) {
      c0 = 0.f; c1 = 0.f; c2 = 1.f; d1 = 0.f; d2 = 0.f; al = 1.f; be = 0.f;
    } else if (t == 2) {
      c0 = 0.f; c1 = 0.5f; c2 = 0.5f; d1 = 0.5f; d2 = 0.5f; al = 0.5f; be = 0.5f;
    } else {
      c0 = (t == 3) ? is6 : (1.f / 3.f);
      c1 = 1.f / 3.f; c2 = is6;
      d1 = is6; d2 = 0.5f;
      al = is6; be = 0.5f;
    }
    const int rm1 = (t >= 1) ? rr - 1 : rr;
    const int rm2 = (t >= 2) ? rr - 2 : rr;
    ushort4 uo;
    unsigned short* up = (unsigned short*)&uo;
#pragma unroll
    for (int j = 0; j < 4; ++j) {
      const int c = c4 + j;
      const float gc = Gs[rr][c], gb = Gs[rm1][c], ga = Gs[rm2][c];
      const float bb = b1[col0 + c];
      const float h1a = fmaxf(c0 * ga + c1 * gb + c2 * gc + bb, 0.f);
      const float h1b = fmaxf(d1 * gb + d2 * gc + bb, 0.f);
      up[j] = f2bf(al * h1a + be * h1b);
    }
    *reinterpret_cast<ushort4*>(&Ut[rr][c4]) = uo;
  }

  // Store W2 slice to LDS, transposed to [n][k] bf16 (waits on w2r loads).
  {
    const int n = tid & 255, kq = tid >> 8;
    bf16x8 v0, v1;
#pragma unroll
    for (int kk = 0; kk < 8; ++kk) v0[kk] = (short)f2bf(w2r[kk]);
#pragma unroll
    for (int kk = 0; kk < 8; ++kk) v1[kk] = (short)f2bf(w2r[8 + kk]);
    *reinterpret_cast<bf16x8*>(&W2t[n][kq * 16]) = v0;
    *reinterpret_cast<bf16x8*>(&W2t[n][kq * 16 + 8]) = v1;
  }
  __syncthreads();

  // GEMM2 K-slice partial: wave w8: rows (w8&3)*16.., N-half (w8>>2)*128..
  {
    const int rowq = (w8 & 3) * 16;
    const int n0 = (w8 >> 2) * 128;
    const bf16x8 af = *reinterpret_cast<const bf16x8*>(&Ut[rowq + lr][lk]);
    f32x4 pacc[8];
#pragma unroll
    for (int j = 0; j < 8; ++j) {
      const bf16x8 bfj =
          *reinterpret_cast<const bf16x8*>(&W2t[n0 + j * 16 + lr][lk]);
      f32x4 z = {0.f, 0.f, 0.f, 0.f};
      pacc[j] = __builtin_amdgcn_mfma_f32_16x16x32_bf16(af, bfj, z, 0, 0, 0);
    }
    float* P = Pp + (size_t)ct * ROWS * OO;
    const int crow = row0 + rowq + (lane >> 4) * 4;
#pragma unroll
    for (int j = 0; j < 8; ++j)
#pragma unroll
      for (int i = 0; i < 4; ++i)
        P[(size_t)(crow + i) * OO + n0 + j * 16 + lr] = pacc[j][i];
  }
}

// ---------------------------------------------------------------------------
// k3: tgt = relu(sum of 16 partials + b2); out = tgt @ Wl + bl.
// 8 rows/block, 128 blocks.
// ---------------------------------------------------------------------------
__global__ __launch_bounds__(256) void k3_head16(
    const float* __restrict__ Pp, const float* __restrict__ b2,
    const float* __restrict__ Wl, const float* __restrict__ bl,
    float* __restrict__ out) {
  __shared__ float sW[OO * AA];
  __shared__ float sT[8][OO + 8];

  constexpr size_t TSZ = (size_t)ROWS * OO;
  const int tid = threadIdx.x;
  for (int i = tid; i < OO * AA; i += 256) sW[i] = Wl[i];
  const int r0 = blockIdx.x * 8;
#pragma unroll
  for (int q = 0; q < 2; ++q) {
    const int idx4 = tid + q * 256;        // 0..511 float4 slots
    const int m = idx4 >> 6;               // row 0..7
    const int k4 = (idx4 & 63) * 4;        // col
    const float* p = &Pp[(size_t)(r0 + m) * OO + k4];
    float4 s = *reinterpret_cast<const float4*>(&b2[k4]);
#pragma unroll
    for (int z = 0; z < 16; ++z) {
      const float4 v = *reinterpret_cast<const float4*>(&p[z * TSZ]);
      s.x += v.x; s.y += v.y; s.z += v.z; s.w += v.w;
    }
    sT[m][k4 + 0] = fmaxf(s.x, 0.f);
    sT[m][k4 + 1] = fmaxf(s.y, 0.f);
    sT[m][k4 + 2] = fmaxf(s.z, 0.f);
    sT[m][k4 + 3] = fmaxf(s.w, 0.f);
  }
  __syncthreads();

  if (tid < 8 * AA) {
    const int m = tid / AA;
    const int o = tid - m * AA;
    float s = bl[o];
#pragma unroll 8
    for (int k = 0; k < OO; ++k) s = fmaf(sT[m][k], sW[k * AA + o], s);
    out[(size_t)(r0 + m) * AA + o] = s;
  }
}

extern "C" void kernel_launch(void* const* d_in, const int* in_sizes, int n_in,
                              void* d_out, int out_size, void* d_ws, size_t ws_size,
                              hipStream_t stream) {
  const float* obs = (const float*)d_in[0];   // [1024, 512]
  const float* W1 = (const float*)d_in[4];    // [512, 512]
  const float* b1 = (const float*)d_in[5];    // [512]
  const float* W2 = (const float*)d_in[6];    // [512, 256]
  const float* b2 = (const float*)d_in[7];    // [256]
  const float* Wl = (const float*)d_in[8];    // [256, 18]
  const float* bl = (const float*)d_in[9];    // [18]
  float* out = (float*)d_out;                 // [1024, 18]

  float* Pp = (float*)d_ws;   // 16 x 1024 x 256 f32 = 16 MiB partials

  // 1) GEMM1 + combine + GEMM2-Kslice partials. 256 blocks x 512 thr.
  k1_mega<<<256, 512, 0, stream>>>(obs, W1, b1, W2, Pp);

  // 2) reduce 16 partials + b2 + relu + head. 128 blocks.
  k3_head16<<<ROWS / 8, 256, 0, stream>>>(Pp, b2, Wl, bl, out);
}